// Round 1
// baseline (390.116 us; speedup 1.0000x reference)
//
#include <hip/hip_runtime.h>
#include <math.h>

// Problem constants (match reference file)
#define NB 16              // batch
#define NPIX 1048576       // H*W = 1024*1024
#define BINS 4096
#define CHUNKS 32          // blocks per sample in pass A (big-ws path)
#define TPB_A 512
#define PIX_PER_BLOCK (NPIX / CHUNKS)   // 32768
#define TPB_B 256
#define BLOSS_MAX 16.2f    // > -log(1e-7) = 16.118
#define EPS_F 1e-7f

// store_mode: 0 = per-block plain stores (hist at blk*BINS), 1 = global atomics
// into per-sample hist (hist at b*BINS) + atomic f_sum[b].
__global__ __launch_bounds__(TPB_A) void pass_a(
    const float* __restrict__ probs, const float* __restrict__ gt,
    unsigned* __restrict__ g_cnt, float* __restrict__ g_sum,
    float* __restrict__ partial_f, int store_mode)
{
    __shared__ unsigned s_cnt[BINS];
    __shared__ float s_sum[BINS];
    __shared__ float s_red[TPB_A / 64];

    const int tid = threadIdx.x;
    for (int j = tid; j < BINS; j += TPB_A) { s_cnt[j] = 0u; s_sum[j] = 0.f; }
    __syncthreads();

    const int blk = blockIdx.x;
    const int b = blk >> 5;            // / CHUNKS
    const int chunk = blk & (CHUNKS - 1);
    const float* p0 = probs + (size_t)b * 2 * NPIX;
    const float* p1 = p0 + NPIX;
    const float* gp = gt + (size_t)b * NPIX;
    const int base = chunk * PIX_PER_BLOCK;
    const float scale = (float)BINS / BLOSS_MAX;

    float f_acc = 0.f;
    const int iters = PIX_PER_BLOCK / (TPB_A * 4);   // 16
    for (int it = 0; it < iters; ++it) {
        const int i = base + ((it * TPB_A + tid) << 2);
        const float4 a0 = *(const float4*)(p0 + i);
        const float4 a1 = *(const float4*)(p1 + i);
        const float4 gg = *(const float4*)(gp + i);
        float dv[4] = {a1.x - a0.x, a1.y - a0.y, a1.z - a0.z, a1.w - a0.w};
        float gv[4] = {gg.x, gg.y, gg.z, gg.w};
        #pragma unroll
        for (int q = 0; q < 4; ++q) {
            float pc = 1.f / (1.f + __expf(-dv[q]));
            pc = fminf(fmaxf(pc, EPS_F), 1.f - EPS_F);
            if (gv[q] > 0.5f) {
                f_acc -= __logf(pc);      // foreground: f_loss, b_loss == 0
            } else {
                float bl = -__logf(1.f - pc);   // > 0 always (pc <= 1-eps)
                int bin = (int)(bl * scale);
                bin = bin < (BINS - 1) ? bin : (BINS - 1);
                atomicAdd(&s_cnt[bin], 1u);
                atomicAdd(&s_sum[bin], bl);
            }
        }
    }
    __syncthreads();

    if (store_mode == 0) {
        for (int j = tid; j < BINS; j += TPB_A) {
            g_cnt[(size_t)blk * BINS + j] = s_cnt[j];
            g_sum[(size_t)blk * BINS + j] = s_sum[j];
        }
    } else {
        for (int j = tid; j < BINS; j += TPB_A) {
            if (s_cnt[j]) {
                atomicAdd(&g_cnt[(size_t)b * BINS + j], s_cnt[j]);
                atomicAdd(&g_sum[(size_t)b * BINS + j], s_sum[j]);
            }
        }
    }

    // block-reduce f_acc (wave shuffle then cross-wave via LDS)
    #pragma unroll
    for (int o = 32; o > 0; o >>= 1) f_acc += __shfl_down(f_acc, o, 64);
    if ((tid & 63) == 0) s_red[tid >> 6] = f_acc;
    __syncthreads();
    if (tid == 0) {
        float s = 0.f;
        #pragma unroll
        for (int w = 0; w < TPB_A / 64; ++w) s += s_red[w];
        if (store_mode == 0) partial_f[blk] = s;
        else atomicAdd(&partial_f[b], s);
    }
}

// One block per sample. chunks = #per-block histograms to reduce (CHUNKS or 1).
__global__ __launch_bounds__(TPB_B) void pass_b(
    const unsigned* __restrict__ g_cnt, const float* __restrict__ g_sum,
    const float* __restrict__ partial_f, const float* __restrict__ gt_f_num,
    float* __restrict__ terms, int chunks)
{
    __shared__ unsigned s_cnt[BINS];
    __shared__ float s_sum[BINS];
    __shared__ unsigned s_ccnt[TPB_B];
    __shared__ double s_csum[TPB_B];

    const int b = blockIdx.x;
    const int t = threadIdx.x;

    // reduce per-block histograms -> per-sample histogram in LDS (coalesced)
    for (int j = 0; j < BINS / TPB_B; ++j) {
        const int bin = j * TPB_B + t;
        unsigned c = 0; float s = 0.f;
        for (int k = 0; k < chunks; ++k) {
            const size_t off = ((size_t)(b * chunks + k)) * BINS + bin;
            c += g_cnt[off];
            s += g_sum[off];
        }
        s_cnt[bin] = c; s_sum[bin] = s;
    }
    __syncthreads();

    // per-thread chunk (16 contiguous bins) totals
    {
        unsigned c = 0; double s = 0.0;
        #pragma unroll
        for (int j = 0; j < BINS / TPB_B; ++j) {
            c += s_cnt[t * (BINS / TPB_B) + j];
            s += (double)s_sum[t * (BINS / TPB_B) + j];
        }
        s_ccnt[t] = c; s_csum[t] = s;
    }
    __syncthreads();

    if (t == 0) {
        float fs = 0.f;
        for (int k = 0; k < chunks; ++k) fs += partial_f[b * chunks + k];

        const long long kk = (long long)gt_f_num[b];
        unsigned long long n_pos = 0; double S_total = 0.0;
        for (int c = 0; c < TPB_B; ++c) { n_pos += s_ccnt[c]; S_total += s_csum[c]; }

        double difficult_sum, difficult_num;
        if (kk <= 0) {
            difficult_sum = 0.0; difficult_num = 0.0;
        } else if ((unsigned long long)kk >= n_pos) {
            difficult_sum = S_total; difficult_num = (double)n_pos;
        } else {
            unsigned long long cum = 0; double Sa = 0.0;
            int cc = TPB_B - 1;
            for (; cc >= 0; --cc) {
                if (cum + s_ccnt[cc] >= (unsigned long long)kk) break;
                cum += s_ccnt[cc]; Sa += s_csum[cc];
            }
            int bstar = cc * (BINS / TPB_B);   // fallback, overwritten below
            for (int j = (BINS / TPB_B) - 1; j >= 0; --j) {
                const int bin = cc * (BINS / TPB_B) + j;
                if (cum + s_cnt[bin] >= (unsigned long long)kk) { bstar = bin; break; }
                cum += s_cnt[bin]; Sa += (double)s_sum[bin];
            }
            const double jtake = (double)(kk - (long long)cum);
            const double avg = (s_cnt[bstar] > 0)
                ? ((double)s_sum[bstar] / (double)s_cnt[bstar]) : 0.0;
            difficult_sum = Sa + jtake * avg;
            difficult_num = (double)kk;
        }

        const double simple_sum = S_total - difficult_sum;
        const double gfn = (double)gt_f_num[b];
        const double term = difficult_sum / (difficult_num + 1e-16)
                          + (double)fs / (gfn + 1e-16)
                          + simple_sum / ((double)NPIX + 1e-16);
        terms[b] = (float)term;
    }
}

__global__ void pass_c(const float* __restrict__ terms, float* __restrict__ out)
{
    if (threadIdx.x == 0 && blockIdx.x == 0) {
        float s = 0.f;
        #pragma unroll
        for (int i = 0; i < NB; ++i) s += terms[i];
        out[0] = s / (float)NB;
    }
}

extern "C" void kernel_launch(void* const* d_in, const int* in_sizes, int n_in,
                              void* d_out, int out_size, void* d_ws, size_t ws_size,
                              hipStream_t stream) {
    const float* probs = (const float*)d_in[0];
    const float* gt    = (const float*)d_in[1];
    const float* gfn   = (const float*)d_in[2];
    char* ws = (char*)d_ws;

    const size_t big_hist_elems = (size_t)NB * CHUNKS * BINS;        // 2M
    const size_t big_need = big_hist_elems * 8                       // cnt+sum
                          + (NB * CHUNKS + NB) * sizeof(float) + 256;

    if (ws_size >= big_need) {
        // big-ws path: per-block histograms, plain stores, no memset needed
        unsigned* g_cnt   = (unsigned*)ws;
        float*    g_sum   = (float*)(ws + big_hist_elems * 4);
        float*    part_f  = (float*)(ws + big_hist_elems * 8);
        float*    terms   = part_f + NB * CHUNKS;
        hipLaunchKernelGGL(pass_a, dim3(NB * CHUNKS), dim3(TPB_A), 0, stream,
                           probs, gt, g_cnt, g_sum, part_f, 0);
        hipLaunchKernelGGL(pass_b, dim3(NB), dim3(TPB_B), 0, stream,
                           g_cnt, g_sum, part_f, gfn, terms, CHUNKS);
        hipLaunchKernelGGL(pass_c, dim3(1), dim3(64), 0, stream,
                           terms, (float*)d_out);
    } else {
        // small-ws fallback: per-sample histograms via global atomics
        const size_t hist_elems = (size_t)NB * BINS;                 // 64K
        unsigned* g_cnt  = (unsigned*)ws;
        float*    g_sum  = (float*)(ws + hist_elems * 4);
        float*    f_sum  = (float*)(ws + hist_elems * 8);
        float*    terms  = f_sum + NB;
        hipMemsetAsync(ws, 0, hist_elems * 8 + 2 * NB * sizeof(float), stream);
        hipLaunchKernelGGL(pass_a, dim3(NB * CHUNKS), dim3(TPB_A), 0, stream,
                           probs, gt, g_cnt, g_sum, f_sum, 1);
        hipLaunchKernelGGL(pass_b, dim3(NB), dim3(TPB_B), 0, stream,
                           g_cnt, g_sum, f_sum, gfn, terms, 1);
        hipLaunchKernelGGL(pass_c, dim3(1), dim3(64), 0, stream,
                           terms, (float*)d_out);
    }
}

// Round 2
// 276.288 us; speedup vs baseline: 1.4120x; 1.4120x over previous
//
#include <hip/hip_runtime.h>
#include <math.h>

// Problem constants (match reference file)
#define NB 16              // batch
#define NPIX 1048576       // H*W = 1024*1024
#define BINS 4096
#define CHUNKS 64          // blocks per sample in pass A
#define TPB_A 512
#define PIX_PER_BLOCK (NPIX / CHUNKS)   // 16384
#define TPB_B 256
#define BLOSS_MAX 16.2f    // > cap 15.9424
#define B_CAP 15.9424f     // -logf(1 - (1-1e-7f)) in float = -log(2^-23); never hit for N(0,sqrt2) data
#define F_CAP 16.1181f     // -logf(1e-7f); never hit either

// FP atomics: guarantee native ds_add_f32 / global_atomic_add_f32 (no CAS loop)
__device__ __forceinline__ void fadd_lds(float* p, float v) {
    __hip_atomic_fetch_add(p, v, __ATOMIC_RELAXED, __HIP_MEMORY_SCOPE_WORKGROUP);
}
__device__ __forceinline__ void fadd_glb(float* p, float v) {
    __hip_atomic_fetch_add(p, v, __ATOMIC_RELAXED, __HIP_MEMORY_SCOPE_AGENT);
}

__global__ __launch_bounds__(TPB_A) void pass_a(
    const float* __restrict__ probs, const float* __restrict__ gt,
    unsigned* __restrict__ g_cnt, float* __restrict__ g_sum,
    float* __restrict__ f_sum)
{
    __shared__ unsigned s_cnt[BINS];
    __shared__ float s_sum[BINS];
    __shared__ float s_red[TPB_A / 64];

    const int tid = threadIdx.x;
    for (int j = tid; j < BINS; j += TPB_A) { s_cnt[j] = 0u; s_sum[j] = 0.f; }
    __syncthreads();

    const int blk = blockIdx.x;
    const int b = blk / CHUNKS;
    const int chunk = blk % CHUNKS;
    const float* p0 = probs + (size_t)b * 2 * NPIX;
    const float* p1 = p0 + NPIX;
    const float* gp = gt + (size_t)b * NPIX;
    const int base = chunk * PIX_PER_BLOCK;
    const float scale = (float)BINS / BLOSS_MAX;

    float f_acc = 0.f;
    const int iters = PIX_PER_BLOCK / (TPB_A * 4);   // 8
    for (int it = 0; it < iters; ++it) {
        const int i = base + ((it * TPB_A + tid) << 2);
        const float4 a0 = *(const float4*)(p0 + i);
        const float4 a1 = *(const float4*)(p1 + i);
        const float4 gg = *(const float4*)(gp + i);
        float dv[4] = {a1.x - a0.x, a1.y - a0.y, a1.z - a0.z, a1.w - a0.w};
        float gv[4] = {gg.x, gg.y, gg.z, gg.w};
        #pragma unroll
        for (int q = 0; q < 4; ++q) {
            // softplus identity: -log(1-sigmoid(d)) = softplus(d),
            // -log(sigmoid(d)) = softplus(-d) = softplus(d) - d.
            // Stable: softplus(d) = max(d,0) + log(1+exp(-|d|)). One exp, one log.
            const float d = dv[q];
            const float t = __logf(1.f + __expf(-fabsf(d)));
            if (gv[q] > 0.5f) {
                f_acc += fminf(fmaxf(-d, 0.f) + t, F_CAP);   // foreground
            } else {
                const float bl = fminf(fmaxf(d, 0.f) + t, B_CAP);
                int bin = (int)(bl * scale);
                bin = bin < (BINS - 1) ? bin : (BINS - 1);
                atomicAdd(&s_cnt[bin], 1u);
                fadd_lds(&s_sum[bin], bl);
            }
        }
    }
    __syncthreads();

    // flush per-block LDS histogram into per-sample global histogram
    for (int j = tid; j < BINS; j += TPB_A) {
        const unsigned c = s_cnt[j];
        if (c) {
            atomicAdd(&g_cnt[(size_t)b * BINS + j], c);
            fadd_glb(&g_sum[(size_t)b * BINS + j], s_sum[j]);
        }
    }

    // block-reduce f_acc
    #pragma unroll
    for (int o = 32; o > 0; o >>= 1) f_acc += __shfl_down(f_acc, o, 64);
    if ((tid & 63) == 0) s_red[tid >> 6] = f_acc;
    __syncthreads();
    if (tid == 0) {
        float s = 0.f;
        #pragma unroll
        for (int w = 0; w < TPB_A / 64; ++w) s += s_red[w];
        fadd_glb(&f_sum[b], s);
    }
}

// One block per sample; per-sample histogram is already reduced in global.
__global__ __launch_bounds__(TPB_B) void pass_b(
    const unsigned* __restrict__ g_cnt, const float* __restrict__ g_sum,
    const float* __restrict__ f_sum, const float* __restrict__ gt_f_num,
    float* __restrict__ terms)
{
    __shared__ unsigned s_cnt[BINS];
    __shared__ float s_sum[BINS];
    __shared__ unsigned s_ccnt[TPB_B];
    __shared__ double s_csum[TPB_B];

    const int b = blockIdx.x;
    const int t = threadIdx.x;

    for (int j = 0; j < BINS / TPB_B; ++j) {
        const int bin = j * TPB_B + t;
        s_cnt[bin] = g_cnt[(size_t)b * BINS + bin];
        s_sum[bin] = g_sum[(size_t)b * BINS + bin];
    }
    __syncthreads();

    // per-thread chunk (16 contiguous bins) totals
    {
        unsigned c = 0; double s = 0.0;
        #pragma unroll
        for (int j = 0; j < BINS / TPB_B; ++j) {
            c += s_cnt[t * (BINS / TPB_B) + j];
            s += (double)s_sum[t * (BINS / TPB_B) + j];
        }
        s_ccnt[t] = c; s_csum[t] = s;
    }
    __syncthreads();

    if (t == 0) {
        const float fs = f_sum[b];
        const long long kk = (long long)gt_f_num[b];
        unsigned long long n_pos = 0; double S_total = 0.0;
        for (int c = 0; c < TPB_B; ++c) { n_pos += s_ccnt[c]; S_total += s_csum[c]; }

        double difficult_sum, difficult_num;
        if (kk <= 0) {
            difficult_sum = 0.0; difficult_num = 0.0;
        } else if ((unsigned long long)kk >= n_pos) {
            difficult_sum = S_total; difficult_num = (double)n_pos;
        } else {
            unsigned long long cum = 0; double Sa = 0.0;
            int cc = TPB_B - 1;
            for (; cc >= 0; --cc) {
                if (cum + s_ccnt[cc] >= (unsigned long long)kk) break;
                cum += s_ccnt[cc]; Sa += s_csum[cc];
            }
            int bstar = cc * (BINS / TPB_B);
            for (int j = (BINS / TPB_B) - 1; j >= 0; --j) {
                const int bin = cc * (BINS / TPB_B) + j;
                if (cum + s_cnt[bin] >= (unsigned long long)kk) { bstar = bin; break; }
                cum += s_cnt[bin]; Sa += (double)s_sum[bin];
            }
            const double jtake = (double)(kk - (long long)cum);
            const double avg = (s_cnt[bstar] > 0)
                ? ((double)s_sum[bstar] / (double)s_cnt[bstar]) : 0.0;
            difficult_sum = Sa + jtake * avg;
            difficult_num = (double)kk;
        }

        const double simple_sum = S_total - difficult_sum;
        const double gfn = (double)gt_f_num[b];
        const double term = difficult_sum / (difficult_num + 1e-16)
                          + (double)fs / (gfn + 1e-16)
                          + simple_sum / ((double)NPIX + 1e-16);
        terms[b] = (float)term;
    }
}

__global__ void pass_c(const float* __restrict__ terms, float* __restrict__ out)
{
    if (threadIdx.x == 0 && blockIdx.x == 0) {
        float s = 0.f;
        #pragma unroll
        for (int i = 0; i < NB; ++i) s += terms[i];
        out[0] = s / (float)NB;
    }
}

extern "C" void kernel_launch(void* const* d_in, const int* in_sizes, int n_in,
                              void* d_out, int out_size, void* d_ws, size_t ws_size,
                              hipStream_t stream) {
    const float* probs = (const float*)d_in[0];
    const float* gt    = (const float*)d_in[1];
    const float* gfn   = (const float*)d_in[2];
    char* ws = (char*)d_ws;

    const size_t hist_elems = (size_t)NB * BINS;                 // 64K
    unsigned* g_cnt  = (unsigned*)ws;
    float*    g_sum  = (float*)(ws + hist_elems * 4);
    float*    f_sum  = (float*)(ws + hist_elems * 8);            // NB floats
    float*    terms  = f_sum + NB;                               // NB floats

    // zero cnt+sum+f_sum (ws is re-poisoned to 0xAA before every launch)
    hipMemsetAsync(ws, 0, hist_elems * 8 + NB * sizeof(float), stream);

    hipLaunchKernelGGL(pass_a, dim3(NB * CHUNKS), dim3(TPB_A), 0, stream,
                       probs, gt, g_cnt, g_sum, f_sum);
    hipLaunchKernelGGL(pass_b, dim3(NB), dim3(TPB_B), 0, stream,
                       g_cnt, g_sum, f_sum, gfn, terms);
    hipLaunchKernelGGL(pass_c, dim3(1), dim3(64), 0, stream,
                       terms, (float*)d_out);
}

// Round 3
// 244.233 us; speedup vs baseline: 1.5973x; 1.1312x over previous
//
#include <hip/hip_runtime.h>
#include <math.h>

// Problem constants (match reference file)
#define NB 16
#define NPIX 1048576                       // 1024*1024
#define BINS 4096
#define CHUNKS 64                          // blocks per sample in pass A
#define TPB_A 512
#define PIX_PER_BLOCK (NPIX / CHUNKS)      // 16384
#define PPT 8                              // pixels per thread per iter
#define ITERS_A (PIX_PER_BLOCK / (TPB_A * PPT))   // 4
#define TPB_B 256
#define BINS_PER_CHUNK (BINS / TPB_B)      // 16
#define BLOSS_MAX 16.2f
#define BINW (BLOSS_MAX / (float)BINS)
#define B_CAP 15.9424f                     // -log(1-(1-1e-7f)) in f32 = -log(2*2^-24)
#define F_CAP 16.1181f                     // -log(1e-7f)

__device__ __forceinline__ void fadd_glb(float* p, float v) {
    __hip_atomic_fetch_add(p, v, __ATOMIC_RELAXED, __HIP_MEMORY_SCOPE_AGENT);
}

__global__ __launch_bounds__(TPB_A) void pass_a(
    const float* __restrict__ probs, const float* __restrict__ gt,
    unsigned* __restrict__ g_cnt, float* __restrict__ f_sum,
    float* __restrict__ b_sum)
{
    __shared__ unsigned s_cnt[BINS];          // count-only histogram (16 KB)
    __shared__ float s_redf[TPB_A / 64];
    __shared__ float s_redb[TPB_A / 64];

    const int tid = threadIdx.x;
    for (int j = tid; j < BINS; j += TPB_A) s_cnt[j] = 0u;
    __syncthreads();

    const int blk = blockIdx.x;
    const int b = blk / CHUNKS;
    const int chunk = blk % CHUNKS;
    const float* p0 = probs + (size_t)b * 2 * NPIX;
    const float* p1 = p0 + NPIX;
    const float* gp = gt + (size_t)b * NPIX;
    const int base = chunk * PIX_PER_BLOCK;
    const float scale = (float)BINS / BLOSS_MAX;

    float f_acc = 0.f, b_acc = 0.f;

    // register double-buffer: 6 float4 loads in flight ahead of compute
    float4 cA0, cB0, cA1, cB1, cG0, cG1;
    {
        const int i = base + (tid << 2);
        const int i2 = i + TPB_A * 4;
        cA0 = *(const float4*)(p0 + i);  cB0 = *(const float4*)(p0 + i2);
        cA1 = *(const float4*)(p1 + i);  cB1 = *(const float4*)(p1 + i2);
        cG0 = *(const float4*)(gp + i);  cG1 = *(const float4*)(gp + i2);
    }
    for (int it = 0; it < ITERS_A; ++it) {
        float4 nA0, nB0, nA1, nB1, nG0, nG1;
        {
            const int nit = (it + 1 < ITERS_A) ? it + 1 : it;  // last: L1-hit reload
            const int i = base + nit * (TPB_A * PPT) + (tid << 2);
            const int i2 = i + TPB_A * 4;
            nA0 = *(const float4*)(p0 + i);  nB0 = *(const float4*)(p0 + i2);
            nA1 = *(const float4*)(p1 + i);  nB1 = *(const float4*)(p1 + i2);
            nG0 = *(const float4*)(gp + i);  nG1 = *(const float4*)(gp + i2);
        }
        const float dv[PPT] = {cA1.x - cA0.x, cA1.y - cA0.y, cA1.z - cA0.z, cA1.w - cA0.w,
                               cB1.x - cB0.x, cB1.y - cB0.y, cB1.z - cB0.z, cB1.w - cB0.w};
        const float gv[PPT] = {cG0.x, cG0.y, cG0.z, cG0.w, cG1.x, cG1.y, cG1.z, cG1.w};
        #pragma unroll
        for (int q = 0; q < PPT; ++q) {
            // -log(1-sigmoid(d)) = softplus(d); -log(sigmoid(d)) = softplus(d)-d
            const float d = dv[q];
            const float sp = fmaxf(d, 0.f) + __logf(1.f + __expf(-fabsf(d)));
            if (gv[q] > 0.5f) {
                f_acc += fminf(sp - d, F_CAP);          // foreground loss (exact)
            } else {
                const float bl = fminf(sp, B_CAP);
                b_acc += bl;                             // exact total bg sum
                int bin = (int)(bl * scale);
                bin = bin < (BINS - 1) ? bin : (BINS - 1);
                atomicAdd(&s_cnt[bin], 1u);              // ONE LDS atomic per bg pixel
            }
        }
        cA0 = nA0; cB0 = nB0; cA1 = nA1; cB1 = nB1; cG0 = nG0; cG1 = nG1;
    }
    __syncthreads();

    // flush count histogram to per-sample global histogram (skip zeros)
    for (int j = tid; j < BINS; j += TPB_A) {
        const unsigned c = s_cnt[j];
        if (c) atomicAdd(&g_cnt[(size_t)b * BINS + j], c);
    }

    // block-reduce f_acc / b_acc
    #pragma unroll
    for (int o = 32; o > 0; o >>= 1) {
        f_acc += __shfl_down(f_acc, o, 64);
        b_acc += __shfl_down(b_acc, o, 64);
    }
    if ((tid & 63) == 0) { s_redf[tid >> 6] = f_acc; s_redb[tid >> 6] = b_acc; }
    __syncthreads();
    if (tid == 0) {
        float f = 0.f, bs = 0.f;
        #pragma unroll
        for (int w = 0; w < TPB_A / 64; ++w) { f += s_redf[w]; bs += s_redb[w]; }
        fadd_glb(&f_sum[b], f);
        fadd_glb(&b_sum[b], bs);
    }
}

// One block per sample. Top-k threshold from count histogram via suffix scan.
__global__ __launch_bounds__(TPB_B) void pass_b(
    const unsigned* __restrict__ g_cnt, const float* __restrict__ f_sum,
    const float* __restrict__ b_sum, const float* __restrict__ gt_f_num,
    float* __restrict__ terms)
{
    __shared__ unsigned s_cnt[BINS];
    __shared__ unsigned s_suf[TPB_B];
    __shared__ double s_wsuf[TPB_B];
    __shared__ double s_dsum;

    const int b = blockIdx.x;
    const int t = threadIdx.x;

    for (int j = 0; j < BINS_PER_CHUNK; ++j) {
        const int bin = j * TPB_B + t;
        s_cnt[bin] = g_cnt[(size_t)b * BINS + bin];
    }
    __syncthreads();

    // per-chunk count and midpoint-weighted sum
    unsigned c = 0; double w = 0.0;
    const int cb = t * BINS_PER_CHUNK;
    for (int j = 0; j < BINS_PER_CHUNK; ++j) {
        const unsigned cc = s_cnt[cb + j];
        c += cc;
        w += (double)cc * (double)(((float)(cb + j) + 0.5f) * BINW);
    }
    s_suf[t] = c; s_wsuf[t] = w;
    __syncthreads();

    // Hillis-Steele inclusive suffix scan over 256 chunks
    for (int off = 1; off < TPB_B; off <<= 1) {
        const unsigned ac = (t + off < TPB_B) ? s_suf[t + off] : 0u;
        const double aw = (t + off < TPB_B) ? s_wsuf[t + off] : 0.0;
        __syncthreads();
        s_suf[t] += ac; s_wsuf[t] += aw;
        __syncthreads();
    }

    const long long kk = (long long)gt_f_num[b];
    const unsigned long long n_pos = (unsigned long long)s_suf[0];
    const unsigned long long suf_me = s_suf[t];
    const unsigned long long suf_nx = (t + 1 < TPB_B) ? s_suf[t + 1] : 0ull;

    if (kk > 0 && (unsigned long long)kk < n_pos &&
        suf_nx < (unsigned long long)kk && (unsigned long long)kk <= suf_me) {
        // threshold bin is in my chunk; scan its 16 bins top-down
        unsigned long long cum = suf_nx;
        double W = (t + 1 < TPB_B) ? s_wsuf[t + 1] : 0.0;
        int bstar = cb;
        for (int j = BINS_PER_CHUNK - 1; j >= 0; --j) {
            const int bin = cb + j;
            const unsigned cc = s_cnt[bin];
            if (cum + cc >= (unsigned long long)kk) { bstar = bin; break; }
            cum += cc;
            W += (double)cc * (double)(((float)bin + 0.5f) * BINW);
        }
        const double partial = (double)(kk - (long long)cum);
        s_dsum = W + partial * (double)(((float)bstar + 0.5f) * BINW);
    }
    __syncthreads();

    if (t == 0) {
        const double S_total = (double)b_sum[b];   // exact
        const double fs = (double)f_sum[b];        // exact
        const double gfn = (double)gt_f_num[b];
        double dsum, dnum;
        if (kk <= 0) { dsum = 0.0; dnum = 0.0; }
        else if ((unsigned long long)kk >= n_pos) { dsum = S_total; dnum = (double)n_pos; }
        else { dsum = s_dsum; dnum = (double)kk; }
        const double term = dsum / (dnum + 1e-16)
                          + fs / (gfn + 1e-16)
                          + (S_total - dsum) / ((double)NPIX + 1e-16);
        terms[b] = (float)term;
    }
}

__global__ void pass_c(const float* __restrict__ terms, float* __restrict__ out)
{
    if (threadIdx.x == 0 && blockIdx.x == 0) {
        float s = 0.f;
        #pragma unroll
        for (int i = 0; i < NB; ++i) s += terms[i];
        out[0] = s / (float)NB;
    }
}

extern "C" void kernel_launch(void* const* d_in, const int* in_sizes, int n_in,
                              void* d_out, int out_size, void* d_ws, size_t ws_size,
                              hipStream_t stream) {
    const float* probs = (const float*)d_in[0];
    const float* gt    = (const float*)d_in[1];
    const float* gfn   = (const float*)d_in[2];
    char* ws = (char*)d_ws;

    const size_t hist_bytes = (size_t)NB * BINS * 4;   // 256 KB
    unsigned* g_cnt = (unsigned*)ws;
    float*    f_sum = (float*)(ws + hist_bytes);       // NB
    float*    b_sum = f_sum + NB;                      // NB
    float*    terms = b_sum + NB;                      // NB

    // zero g_cnt + f_sum + b_sum (ws is poisoned to 0xAA before every launch)
    hipMemsetAsync(ws, 0, hist_bytes + 2 * NB * sizeof(float), stream);

    hipLaunchKernelGGL(pass_a, dim3(NB * CHUNKS), dim3(TPB_A), 0, stream,
                       probs, gt, g_cnt, f_sum, b_sum);
    hipLaunchKernelGGL(pass_b, dim3(NB), dim3(TPB_B), 0, stream,
                       g_cnt, f_sum, b_sum, gfn, terms);
    hipLaunchKernelGGL(pass_c, dim3(1), dim3(64), 0, stream,
                       terms, (float*)d_out);
}